// Round 10
// baseline (227.868 us; speedup 1.0000x reference)
//
#include <hip/hip_runtime.h>
#include <math.h>

// ---------------------------------------------------------------------------
// CausalAttention — round 10.
//   QKV GEMM: r7-proven 128x256/512thr tri-buffer counted-vmcnt (71.6us).
//   QK: same template (r7 config), causal block-skip, longest-first.
//   PV+softmax FUSED (pv_fused): flash-style online softmax over the
//   materialized fp32 S (L3-resident). Per block: O[64][256] acc, iterate
//   32-key tiles: S->regs (prefetched), quad/row online m,l,f; P bf16 -> LDS
//   (XOR swizzle, 2-way free); V dbuf via global_load_lds (pre-swizzled);
//   acc rescale by fac[row] (LDS broadcast); 16 MFMA. One vmcnt(0) + two raw
//   barriers per tile (no counted gates -> spill-safe). Epilogue x 1/l.
//   Eliminates the softmax kernel (read 67MB + write 33MB) and P entirely.
// ---------------------------------------------------------------------------

typedef float  f32x4  __attribute__((ext_vector_type(4)));
typedef int    i32x4  __attribute__((ext_vector_type(4)));
typedef __bf16 bf16x8 __attribute__((ext_vector_type(8)));

__device__ inline ushort f2bf(float f) {
    union { float f; unsigned u; } a; a.f = f;
    unsigned u = a.u;
    return (ushort)((u + 0x7fffu + ((u >> 16) & 1u)) >> 16);  // RNE
}
__device__ inline bf16x8 as_bf(i32x4 v) {
    union { i32x4 i; bf16x8 b; } u; u.i = v; return u.b;
}

#define GLDS(gp, lp)                                                         \
    __builtin_amdgcn_global_load_lds(                                        \
        (const __attribute__((address_space(1))) void*)(gp),                 \
        (__attribute__((address_space(3))) void*)(lp), 16, 0, 0)

#define BKK 32

// 16B-chunk XOR swizzle within a 64B LDS row (involution; 0 conflicts, r5)
__device__ inline int swz(int row, int c) { return c ^ ((row >> 1) & 3); }

// ======================= GEMM (QKV + QK) — r7 structure =====================
// MODE 0: plain  1: causal block-skip (scores)
// OUT  0: fp32 C[z][r][c] = v*alpha     OUT 1: bf16 C[r][c] (merged QKV)
template <int BMT, int BNT, int MODE, int OUT>
__global__ __launch_bounds__((BMT / 64) * (BNT / 64) * 64,
                             ((BMT / 64) * (BNT / 64) == 8) ? 4 : 3)
void gemm_bf16(
    const ushort* __restrict__ A, const ushort* __restrict__ B0,
    float* __restrict__ Cf, ushort* __restrict__ Cb,
    int N, int K, int lda, int ldb,
    long long sA, long long sB, long long sC, float alpha)
{
    constexpr int NWC = BNT / 64;
    constexpr int T   = (BMT / 64) * NWC * 64;
    constexpr int RPG = T / 4;
    constexpr int IA  = BMT / RPG;
    constexpr int IB  = BNT / RPG;
    constexpr int L   = IA + IB;
    static_assert(L == 3 || L == 4, "gate literals cover L=3,4");

    A  += (long long)blockIdx.z * sA;
    B0 += (long long)blockIdx.z * sB;

    int byi = blockIdx.y;
    if (MODE != 0) byi = gridDim.y - 1 - byi;   // longest row-blocks first

    const int m0 = byi * BMT;
    const int n0 = blockIdx.x * BNT;
    if (MODE == 1 && n0 > m0 + (BMT - 1)) return;
    const int kend = K;

    __shared__ ushort As[3][BMT * BKK];
    __shared__ ushort Bs[3][BNT * BKK];

    const int tid = threadIdx.x;
    const int l   = tid & 63;
    const int w   = tid >> 6;
    const int g   = l >> 4;
    const int r16 = l & 15;
    const int wr  = w / NWC, wc = w % NWC;

    f32x4 acc[4][4];
#pragma unroll
    for (int mi = 0; mi < 4; ++mi)
#pragma unroll
        for (int ni = 0; ni < 4; ++ni)
            acc[mi][ni] = (f32x4){0.f, 0.f, 0.f, 0.f};

    const int srow = w * 16 + (l >> 2);
    const int cg   = swz(srow, l & 3);
    const ushort* gA = A  + (size_t)(m0 + srow) * lda + cg * 8;
    const ushort* gB = B0 + (size_t)(n0 + srow) * ldb + cg * 8;

#define STAGE(bi, k0)                                                        \
    do {                                                                     \
        _Pragma("unroll")                                                    \
        for (int ia = 0; ia < IA; ++ia)                                      \
            GLDS(gA + (k0) + (size_t)(ia * RPG) * lda,                       \
                 &As[bi][(ia * RPG + w * 16) * BKK]);                        \
        _Pragma("unroll")                                                    \
        for (int ib = 0; ib < IB; ++ib)                                      \
            GLDS(gB + (k0) + (size_t)(ib * RPG) * ldb,                       \
                 &Bs[bi][(ib * RPG + w * 16) * BKK]);                        \
    } while (0)

    const int nt = kend / BKK;
    STAGE(0, 0);
    if (nt > 1) STAGE(1, BKK);

    int cur = 0;
    for (int t = 0; t < nt; ++t) {
        const int nxt = (cur >= 1) ? cur - 1 : 2;
        if (t + 2 < nt) {
            STAGE(nxt, (t + 2) * BKK);
            if constexpr (L == 3)
                asm volatile("s_waitcnt vmcnt(6)" ::: "memory");
            else
                asm volatile("s_waitcnt vmcnt(8)" ::: "memory");
        } else if (t + 1 < nt) {
            if constexpr (L == 3)
                asm volatile("s_waitcnt vmcnt(3)" ::: "memory");
            else
                asm volatile("s_waitcnt vmcnt(4)" ::: "memory");
        } else {
            asm volatile("s_waitcnt vmcnt(0)" ::: "memory");
        }
        __builtin_amdgcn_s_barrier();
        asm volatile("" ::: "memory");

        i32x4 av[4], bv[4];
#pragma unroll
        for (int mi = 0; mi < 4; ++mi) {
            const int r = wr * 64 + mi * 16 + r16;
            av[mi] = *(const i32x4*)(&As[cur][r * BKK + swz(r, g) * 8]);
        }
#pragma unroll
        for (int ni = 0; ni < 4; ++ni) {
            const int r = wc * 64 + ni * 16 + r16;
            bv[ni] = *(const i32x4*)(&Bs[cur][r * BKK + swz(r, g) * 8]);
        }

        __builtin_amdgcn_s_setprio(1);
#pragma unroll
        for (int mi = 0; mi < 4; ++mi)
#pragma unroll
            for (int ni = 0; ni < 4; ++ni)
                acc[mi][ni] = __builtin_amdgcn_mfma_f32_16x16x32_bf16(
                    as_bf(av[mi]), as_bf(bv[ni]), acc[mi][ni], 0, 0, 0);
        __builtin_amdgcn_s_setprio(0);

        asm volatile("" ::: "memory");
        __builtin_amdgcn_s_barrier();
        asm volatile("" ::: "memory");
        cur = (cur == 2) ? 0 : cur + 1;
    }
#undef STAGE

#pragma unroll
    for (int mi = 0; mi < 4; ++mi) {
#pragma unroll
        for (int ni = 0; ni < 4; ++ni) {
#pragma unroll
            for (int rr = 0; rr < 4; ++rr) {
                const int gr = m0 + wr * 64 + mi * 16 + g * 4 + rr;
                const int gc = n0 + wc * 64 + ni * 16 + r16;
                const float v = acc[mi][ni][rr] * alpha;
                if (OUT == 0)
                    Cf[(long long)blockIdx.z * sC + (size_t)gr * N + gc] = v;
                else
                    Cb[(size_t)gr * N + gc] = f2bf(v);
            }
        }
    }
}

// ===================== fused softmax + PV (flash over S) ====================
__global__ __launch_bounds__(256, 3) void pv_fused(
    const float* __restrict__ Sc, const ushort* __restrict__ Vt,
    float* __restrict__ out)
{
    const int b  = blockIdx.z;
    const int by = (int)gridDim.y - 1 - (int)blockIdx.y;  // longest first
    const int m0 = by * 64;
    const int d0 = blockIdx.x * 256;

    const float*  S = Sc + (size_t)b * 4194304;
    const ushort* V = Vt + (size_t)b * 2097152;

    __shared__ ushort Ps[64 * 32];          // P tile, XOR-swizzled
    __shared__ ushort Bs[2][256 * 32];      // V tile dbuf
    __shared__ float  fac[64];
    __shared__ float  lrow[64];

    const int tid = threadIdx.x;
    const int l   = tid & 63;
    const int w   = tid >> 6;               // wave 0..3 (= d-quadrant)
    const int g   = l >> 4;
    const int r16 = l & 15;
    const int xsl = (r16 & 3) ^ ((r16 >> 2) & 3);   // frag-read chunk XOR

    // quad-per-row softmax mapping
    const int qr   = tid >> 2;              // local row 0..63
    const int qc   = tid & 3;               // 8-col slice
    const int grow = m0 + qr;
    const int xsp  = (qr & 3) ^ ((qr >> 2) & 3);

    f32x4 acc[4][4];
#pragma unroll
    for (int mi = 0; mi < 4; ++mi)
#pragma unroll
        for (int ni = 0; ni < 4; ++ni)
            acc[mi][ni] = (f32x4){0.f, 0.f, 0.f, 0.f};

    float m_r = -INFINITY, l_r = 0.f;

    const int nt = (m0 + 64) / 32;          // 2..64 tiles

    // V staging: 4 issues x 64 rows; lane covers row w*16+(l>>2), chunk l&3;
    // source chunk pre-XOR'd so LDS[row][c] = global[row][c ^ xs(row)].
    const int vr  = w * 16 + (l >> 2);
    const int xsv = (vr & 3) ^ ((vr >> 2) & 3);
    const ushort* gV = V + (size_t)(d0 + vr) * 2048 + ((l & 3) ^ xsv) * 8;

#define STAGEV(buf, kt)                                                      \
    do {                                                                     \
        _Pragma("unroll")                                                    \
        for (int is = 0; is < 4; ++is)                                       \
            GLDS(gV + (size_t)(is * 64) * 2048 + (kt) * 32,                  \
                 &Bs[buf][(is * 64 + w * 16) * 32]);                         \
    } while (0)

    const float* gS = S + (size_t)grow * 2048 + qc * 8;

    STAGEV(0, 0);
    float4 sv0 = *(const float4*)(gS + 0);
    float4 sv1 = *(const float4*)(gS + 4);

    for (int t = 0; t < nt; ++t) {
        asm volatile("s_waitcnt vmcnt(0)" ::: "memory");  // S(t) + V(t) landed

        const int colb = t * 32 + qc * 8;
        float s[8] = {sv0.x, sv0.y, sv0.z, sv0.w, sv1.x, sv1.y, sv1.z, sv1.w};
        float pm = -INFINITY;
#pragma unroll
        for (int i = 0; i < 8; ++i) {
            if (colb + i > grow) s[i] = -INFINITY;
            pm = fmaxf(pm, s[i]);
        }
        pm = fmaxf(pm, __shfl_xor(pm, 1));
        pm = fmaxf(pm, __shfl_xor(pm, 2));
        const float mn = fmaxf(m_r, pm);
        const float f  = __expf(m_r - mn);   // m_r=-inf first iter -> 0
        float p[8], es = 0.f;
#pragma unroll
        for (int i = 0; i < 8; ++i) {
            p[i] = (colb + i <= grow) ? __expf(s[i] - mn) : 0.f;
            es += p[i];
        }
        es += __shfl_xor(es, 1);
        es += __shfl_xor(es, 2);
        l_r = l_r * f + es;
        m_r = mn;
        if (qc == 0) fac[qr] = f;

        unsigned u0 = (unsigned)f2bf(p[0]) | ((unsigned)f2bf(p[1]) << 16);
        unsigned u1 = (unsigned)f2bf(p[2]) | ((unsigned)f2bf(p[3]) << 16);
        unsigned u2 = (unsigned)f2bf(p[4]) | ((unsigned)f2bf(p[5]) << 16);
        unsigned u3 = (unsigned)f2bf(p[6]) | ((unsigned)f2bf(p[7]) << 16);

        asm volatile("" ::: "memory");
        __builtin_amdgcn_s_barrier();       // prev MFMA done; fac visible
        asm volatile("" ::: "memory");

        *(i32x4*)&Ps[qr * 32 + ((qc ^ xsp) * 8)] = (i32x4){
            (int)u0, (int)u1, (int)u2, (int)u3};

        if (t + 1 < nt) {                   // prefetch under compute
            STAGEV((t + 1) & 1, t + 1);
            sv0 = *(const float4*)(gS + (size_t)(t + 1) * 32);
            sv1 = *(const float4*)(gS + (size_t)(t + 1) * 32 + 4);
        }

        // rescale O by fac[row] (16-lane broadcast reads)
#pragma unroll
        for (int mi = 0; mi < 4; ++mi)
#pragma unroll
            for (int rr = 0; rr < 4; ++rr) {
                const float fm = fac[mi * 16 + g * 4 + rr];
#pragma unroll
                for (int ni = 0; ni < 4; ++ni) acc[mi][ni][rr] *= fm;
            }

        asm volatile("" ::: "memory");
        __builtin_amdgcn_s_barrier();       // Ps visible
        asm volatile("" ::: "memory");

        i32x4 av[4], bv[4];
#pragma unroll
        for (int mi = 0; mi < 4; ++mi)
            av[mi] = *(const i32x4*)&Ps[(mi * 16 + r16) * 32 + ((g ^ xsl) * 8)];
#pragma unroll
        for (int ni = 0; ni < 4; ++ni)
            bv[ni] = *(const i32x4*)&Bs[t & 1][(w * 64 + ni * 16 + r16) * 32
                                              + ((g ^ xsl) * 8)];

        __builtin_amdgcn_s_setprio(1);
#pragma unroll
        for (int mi = 0; mi < 4; ++mi)
#pragma unroll
            for (int ni = 0; ni < 4; ++ni)
                acc[mi][ni] = __builtin_amdgcn_mfma_f32_16x16x32_bf16(
                    as_bf(av[mi]), as_bf(bv[ni]), acc[mi][ni], 0, 0, 0);
        __builtin_amdgcn_s_setprio(0);
    }
#undef STAGEV

    if (qc == 0) lrow[qr] = l_r;
    __syncthreads();

#pragma unroll
    for (int mi = 0; mi < 4; ++mi)
#pragma unroll
        for (int rr = 0; rr < 4; ++rr) {
            const float inv = 1.0f / lrow[mi * 16 + g * 4 + rr];
            const size_t ro = (size_t)b * 2097152
                            + (size_t)(m0 + mi * 16 + g * 4 + rr) * 1024;
#pragma unroll
            for (int ni = 0; ni < 4; ++ni)
                out[ro + d0 + w * 64 + ni * 16 + r16] = acc[mi][ni][rr] * inv;
        }
}

// ============================ helpers =======================================
__global__ __launch_bounds__(256) void transpose_v(
    const ushort* __restrict__ QKV, ushort* __restrict__ Vt)
{
    __shared__ ushort t[64][65];
    const int d0 = blockIdx.x * 64;
    const int r0 = blockIdx.y * 64;
    const int tx = threadIdx.x & 31;
    const int ty = threadIdx.x >> 5;

#pragma unroll
    for (int p = 0; p < 8; ++p) {
        const int r = ty + p * 8;
        const ushort2 u = *(const ushort2*)(
            QKV + (size_t)(r0 + r) * 3072 + 2048 + d0 + 2 * tx);
        t[r][2 * tx]     = u.x;
        t[r][2 * tx + 1] = u.y;
    }
    __syncthreads();

    const int b = r0 >> 11, s0 = r0 & 2047;
#pragma unroll
    for (int p = 0; p < 8; ++p) {
        const int d = ty + p * 8;
        ushort2 o;
        o.x = t[2 * tx][d];
        o.y = t[2 * tx + 1][d];
        *(ushort2*)(Vt + (size_t)b * 2097152 + (size_t)(d0 + d) * 2048
                    + s0 + 2 * tx) = o;
    }
}

__global__ void cvt_x(const float4* __restrict__ x, ushort4* __restrict__ o, int n4)
{
    const int i = blockIdx.x * 256 + threadIdx.x;
    if (i < n4) {
        const float4 f = x[i];
        ushort4 u;
        u.x = f2bf(f.x); u.y = f2bf(f.y); u.z = f2bf(f.z); u.w = f2bf(f.w);
        o[i] = u;
    }
}

__global__ __launch_bounds__(256) void cvt_wt(const float* __restrict__ Wq,
                                              const float* __restrict__ Wk,
                                              const float* __restrict__ Wv,
                                              ushort* __restrict__ Wt3)
{
    const float* W = (blockIdx.z == 0) ? Wq : (blockIdx.z == 1) ? Wk : Wv;
    ushort* Wt = Wt3 + (size_t)blockIdx.z * 1048576;

    __shared__ float t[32][33];
    const int tx = threadIdx.x & 31, ty = threadIdx.x >> 5;
    const int c = blockIdx.x * 32 + tx;
    const int rbase = blockIdx.y * 32;
#pragma unroll
    for (int i = 0; i < 4; ++i)
        t[ty + i * 8][tx] = W[(size_t)(rbase + ty + i * 8) * 1024 + c];
    __syncthreads();
    const int kT = blockIdx.y * 32 + tx;
    const int nT = blockIdx.x * 32;
#pragma unroll
    for (int i = 0; i < 4; ++i)
        Wt[(size_t)(nT + ty + i * 8) * 1024 + kT] = f2bf(t[tx][ty + i * 8]);
}

extern "C" void kernel_launch(void* const* d_in, const int* in_sizes, int n_in,
                              void* d_out, int out_size, void* d_ws, size_t ws_size,
                              hipStream_t stream)
{
    (void)in_sizes; (void)n_in; (void)out_size; (void)ws_size;

    const float* x  = (const float*)d_in[0];
    const float* Wq = (const float*)d_in[1];
    const float* Wk = (const float*)d_in[2];
    const float* Wv = (const float*)d_in[3];
    float* out = (float*)d_out;

    const int NB = 4, S = 2048, D = 1024;
    const long long SD  = (long long)S * D;
    const long long NSD = NB * SD;
    const long long SS  = (long long)S * S;

    ushort* xb   = (ushort*)d_ws;
    ushort* Wt3  = xb   + NSD;
    ushort* QKVb = Wt3  + 3 * (size_t)D * D;    // [8192][3072] bf16
    ushort* Vt   = QKVb + (size_t)NB * S * 3 * D;
    float*  Sc   = (float*)(Vt + NSD);          // NB*S*S fp32 scores

    dim3 blk(256), blk5(512);

    cvt_x<<<dim3((unsigned)(NSD / 4 / 256)), blk, 0, stream>>>(
        (const float4*)x, (ushort4*)xb, (int)(NSD / 4));
    cvt_wt<<<dim3(32, 32, 3), blk, 0, stream>>>(Wq, Wk, Wv, Wt3);

    // merged QKV projection: [8192 x 3072 x 1024], 128x256 tiles (r7 cfg)
    dim3 gp(3 * D / 256, (unsigned)(NB * S / 128), 1);
    gemm_bf16<128, 256, 0, 1><<<gp, blk5, 0, stream>>>(
        xb, Wt3, nullptr, QKVb,
        3 * D, D, D, D, 0, 0, 0, 1.f);

    transpose_v<<<dim3(D / 64, (unsigned)(NB * S / 64)), blk, 0, stream>>>(
        QKVb, Vt);

    // scores = Q K^T / 32, 128x256 tiles (r7 cfg), longest rows first
    dim3 gs(S / 256, S / 128, NB);
    gemm_bf16<128, 256, 1, 0><<<gs, blk5, 0, stream>>>(
        QKVb, QKVb + 1024, Sc, nullptr,
        S, D, 3 * D, 3 * D, (long long)S * 3 * D, (long long)S * 3 * D,
        SS, 0.03125f);

    // fused online-softmax + PV
    dim3 gv(D / 256, S / 64, NB);
    pv_fused<<<gv, blk, 0, stream>>>(Sc, Vt, out);
}

// Round 11
// 202.405 us; speedup vs baseline: 1.1258x; 1.1258x over previous
//
#include <hip/hip_runtime.h>
#include <math.h>

// ---------------------------------------------------------------------------
// CausalAttention — round 11.
// r10 post-mortem: pv_fused regressed (101us vs ~55 for softmax+PV separate):
// VALU softmax serialized against a small MFMA tile (MfmaUtil 6.8%). Reverted
// to the r7 pipeline (199.4us best). ONE isolated change vs r7:
//   SINGLE barrier per K-step (r8-verified-correct structure, now at r7's
//   proven tile/occupancy): gate vmcnt(L|0) -> s_barrier -> STAGE(t+2) into
//   buf[(t-1)%3] (provably free: all waves' t-1 ds_reads retired at barrier)
//   -> ds_read(t) -> MFMA. Halves barrier count in QKV/QK/PV.
// Everything else identical to r7: 128x256 tiles, 512thr, tri-buffer 72KB,
// chunk-XOR swizzle (0 conflicts), longest-first causal dispatch, separate
// softmax (fp32 S -> bf16 P in place).
// ---------------------------------------------------------------------------

typedef float  f32x4  __attribute__((ext_vector_type(4)));
typedef int    i32x4  __attribute__((ext_vector_type(4)));
typedef __bf16 bf16x8 __attribute__((ext_vector_type(8)));

__device__ inline ushort f2bf(float f) {
    union { float f; unsigned u; } a; a.f = f;
    unsigned u = a.u;
    return (ushort)((u + 0x7fffu + ((u >> 16) & 1u)) >> 16);  // RNE
}
__device__ inline bf16x8 as_bf(i32x4 v) {
    union { i32x4 i; bf16x8 b; } u; u.i = v; return u.b;
}

#define GLDS(gp, lp)                                                         \
    __builtin_amdgcn_global_load_lds(                                        \
        (const __attribute__((address_space(1))) void*)(gp),                 \
        (__attribute__((address_space(3))) void*)(lp), 16, 0, 0)

#define BKK 32

// 16B-chunk XOR swizzle within a 64B LDS row (involution; 0 conflicts, r5)
__device__ inline int swz(int row, int c) { return c ^ ((row >> 1) & 3); }

// MODE 0: plain  1: causal block-skip (scores)  2: k-clip (PV)
// OUT  0: fp32 C[z][r][c] = v*alpha     OUT 1: bf16 C[r][c] (merged QKV)
template <int BMT, int BNT, int MODE, int OUT>
__global__ __launch_bounds__((BMT / 64) * (BNT / 64) * 64,
                             ((BMT / 64) * (BNT / 64) == 8) ? 4 : 3)
void gemm_bf16(
    const ushort* __restrict__ A, const ushort* __restrict__ B0,
    float* __restrict__ Cf, ushort* __restrict__ Cb,
    int N, int K, int lda, int ldb,
    long long sA, long long sB, long long sC, float alpha)
{
    constexpr int NWC = BNT / 64;
    constexpr int T   = (BMT / 64) * NWC * 64;
    constexpr int RPG = T / 4;                // rows covered per GLDS issue
    constexpr int IA  = BMT / RPG;
    constexpr int IB  = BNT / RPG;
    constexpr int L   = IA + IB;              // GLDS per thread per tile
    static_assert(L == 3 || L == 4, "gate literals cover L=3,4");

    A  += (long long)blockIdx.z * sA;
    B0 += (long long)blockIdx.z * sB;

    int byi = blockIdx.y;
    if (MODE != 0) byi = gridDim.y - 1 - byi;   // longest row-blocks first

    const int m0 = byi * BMT;
    const int n0 = blockIdx.x * BNT;
    if (MODE == 1 && n0 > m0 + (BMT - 1)) return;
    int kend = K;
    if (MODE == 2) kend = min(K, m0 + BMT);     // attn weights 0 beyond

    __shared__ ushort As[3][BMT * BKK];
    __shared__ ushort Bs[3][BNT * BKK];

    const int tid = threadIdx.x;
    const int l   = tid & 63;
    const int w   = tid >> 6;
    const int g   = l >> 4;
    const int r16 = l & 15;
    const int wr  = w / NWC, wc = w % NWC;

    f32x4 acc[4][4];
#pragma unroll
    for (int mi = 0; mi < 4; ++mi)
#pragma unroll
        for (int ni = 0; ni < 4; ++ni)
            acc[mi][ni] = (f32x4){0.f, 0.f, 0.f, 0.f};

    const int srow = w * 16 + (l >> 2);
    const int cg   = swz(srow, l & 3);
    const ushort* gA = A  + (size_t)(m0 + srow) * lda + cg * 8;
    const ushort* gB = B0 + (size_t)(n0 + srow) * ldb + cg * 8;

#define STAGE(bi, k0)                                                        \
    do {                                                                     \
        _Pragma("unroll")                                                    \
        for (int ia = 0; ia < IA; ++ia)                                      \
            GLDS(gA + (k0) + (size_t)(ia * RPG) * lda,                       \
                 &As[bi][(ia * RPG + w * 16) * BKK]);                        \
        _Pragma("unroll")                                                    \
        for (int ib = 0; ib < IB; ++ib)                                      \
            GLDS(gB + (k0) + (size_t)(ib * RPG) * ldb,                       \
                 &Bs[bi][(ib * RPG + w * 16) * BKK]);                        \
    } while (0)

    const int nt = kend / BKK;
    STAGE(0, 0);
    if (nt > 1) STAGE(1, BKK);

    int cur = 0;
    for (int t = 0; t < nt; ++t) {
        // gate: tile t landed (t+1's L loads may stay in flight)
        if (t + 1 < nt) {
            if constexpr (L == 3)
                asm volatile("s_waitcnt vmcnt(3)" ::: "memory");
            else
                asm volatile("s_waitcnt vmcnt(4)" ::: "memory");
        } else {
            asm volatile("s_waitcnt vmcnt(0)" ::: "memory");
        }
        __builtin_amdgcn_s_barrier();   // tile-t visible; t-1 reads retired
        asm volatile("" ::: "memory");

        const int nxt = (cur >= 1) ? cur - 1 : 2;   // (t+2)%3 == (t-1)%3
        if (t + 2 < nt) STAGE(nxt, (t + 2) * BKK);  // flies under MFMA(t..t+1)

        i32x4 av[4], bv[4];
#pragma unroll
        for (int mi = 0; mi < 4; ++mi) {
            const int r = wr * 64 + mi * 16 + r16;
            av[mi] = *(const i32x4*)(&As[cur][r * BKK + swz(r, g) * 8]);
        }
#pragma unroll
        for (int ni = 0; ni < 4; ++ni) {
            const int r = wc * 64 + ni * 16 + r16;
            bv[ni] = *(const i32x4*)(&Bs[cur][r * BKK + swz(r, g) * 8]);
        }

        __builtin_amdgcn_s_setprio(1);
#pragma unroll
        for (int mi = 0; mi < 4; ++mi)
#pragma unroll
            for (int ni = 0; ni < 4; ++ni)
                acc[mi][ni] = __builtin_amdgcn_mfma_f32_16x16x32_bf16(
                    as_bf(av[mi]), as_bf(bv[ni]), acc[mi][ni], 0, 0, 0);
        __builtin_amdgcn_s_setprio(0);

        asm volatile("" ::: "memory");
        cur = (cur == 2) ? 0 : cur + 1;
    }
#undef STAGE

    // epilogue: C/D mapping col=lane&15, row=(lane>>4)*4+reg  [m89-verified]
#pragma unroll
    for (int mi = 0; mi < 4; ++mi) {
#pragma unroll
        for (int ni = 0; ni < 4; ++ni) {
#pragma unroll
            for (int rr = 0; rr < 4; ++rr) {
                const int gr = m0 + wr * 64 + mi * 16 + g * 4 + rr;
                const int gc = n0 + wc * 64 + ni * 16 + r16;
                const float v = acc[mi][ni][rr] * alpha;
                if (OUT == 0)
                    Cf[(long long)blockIdx.z * sC + (size_t)gr * N + gc] = v;
                else
                    Cb[(size_t)gr * N + gc] = f2bf(v);
            }
        }
    }
}

// V slice of merged QKV [8192][3072] (cols 2048..3071) -> Vt[b][d][s]
__global__ __launch_bounds__(256) void transpose_v(
    const ushort* __restrict__ QKV, ushort* __restrict__ Vt)
{
    __shared__ ushort t[64][65];
    const int d0 = blockIdx.x * 64;
    const int r0 = blockIdx.y * 64;          // b*2048+s, 64 | 2048
    const int tx = threadIdx.x & 31;
    const int ty = threadIdx.x >> 5;         // 0..7

#pragma unroll
    for (int p = 0; p < 8; ++p) {
        const int r = ty + p * 8;
        const ushort2 u = *(const ushort2*)(
            QKV + (size_t)(r0 + r) * 3072 + 2048 + d0 + 2 * tx);
        t[r][2 * tx]     = u.x;
        t[r][2 * tx + 1] = u.y;
    }
    __syncthreads();

    const int b = r0 >> 11, s0 = r0 & 2047;
#pragma unroll
    for (int p = 0; p < 8; ++p) {
        const int d = ty + p * 8;
        ushort2 o;
        o.x = t[2 * tx][d];
        o.y = t[2 * tx + 1][d];
        *(ushort2*)(Vt + (size_t)b * 2097152 + (size_t)(d0 + d) * 2048
                    + s0 + 2 * tx) = o;
    }
}

// fp32 scores -> bf16 P in place (row stride 4096 ushorts; zeroed tail).
__global__ __launch_bounds__(256) void softmax_bf16(float* __restrict__ Sc)
{
    const int row = blockIdx.x;
    float* base = Sc + ((size_t)blockIdx.y * 2048 + row) * 2048;
    const int tid = threadIdx.x;

    float v[8];
#pragma unroll
    for (int i = 0; i < 8; ++i) {
        const int j = tid + i * 256;
        v[i] = (j <= row) ? base[j] : -INFINITY;
    }

    __shared__ float red[256];
    float m = -INFINITY;
#pragma unroll
    for (int i = 0; i < 8; ++i) m = fmaxf(m, v[i]);
    red[tid] = m;
    __syncthreads();
    for (int s = 128; s > 0; s >>= 1) {
        if (tid < s) red[tid] = fmaxf(red[tid], red[tid + s]);
        __syncthreads();
    }
    m = red[0];
    __syncthreads();

    float e[8], sum = 0.f;
#pragma unroll
    for (int i = 0; i < 8; ++i) {
        const int j = tid + i * 256;
        e[i] = (j <= row) ? __expf(v[i] - m) : 0.f;
        sum += e[i];
    }
    red[tid] = sum;
    __syncthreads();
    for (int s = 128; s > 0; s >>= 1) {
        if (tid < s) red[tid] += red[tid + s];
        __syncthreads();
    }
    const float inv = 1.f / red[0];

    ushort* pb = (ushort*)base;
#pragma unroll
    for (int i = 0; i < 8; ++i) {
        const int j = tid + i * 256;
        pb[j] = f2bf(e[i] * inv);
    }
}

__global__ void cvt_x(const float4* __restrict__ x, ushort4* __restrict__ o, int n4)
{
    const int i = blockIdx.x * 256 + threadIdx.x;
    if (i < n4) {
        const float4 f = x[i];
        ushort4 u;
        u.x = f2bf(f.x); u.y = f2bf(f.y); u.z = f2bf(f.z); u.w = f2bf(f.w);
        o[i] = u;
    }
}

// W[z] [1024][1024] fp32 -> Wt3 + z*1M : bf16 [n][k] (transpose-convert)
__global__ __launch_bounds__(256) void cvt_wt(const float* __restrict__ Wq,
                                              const float* __restrict__ Wk,
                                              const float* __restrict__ Wv,
                                              ushort* __restrict__ Wt3)
{
    const float* W = (blockIdx.z == 0) ? Wq : (blockIdx.z == 1) ? Wk : Wv;
    ushort* Wt = Wt3 + (size_t)blockIdx.z * 1048576;

    __shared__ float t[32][33];
    const int tx = threadIdx.x & 31, ty = threadIdx.x >> 5;
    const int c = blockIdx.x * 32 + tx;
    const int rbase = blockIdx.y * 32;
#pragma unroll
    for (int i = 0; i < 4; ++i)
        t[ty + i * 8][tx] = W[(size_t)(rbase + ty + i * 8) * 1024 + c];
    __syncthreads();
    const int kT = blockIdx.y * 32 + tx;
    const int nT = blockIdx.x * 32;
#pragma unroll
    for (int i = 0; i < 4; ++i)
        Wt[(size_t)(nT + ty + i * 8) * 1024 + kT] = f2bf(t[tx][ty + i * 8]);
}

extern "C" void kernel_launch(void* const* d_in, const int* in_sizes, int n_in,
                              void* d_out, int out_size, void* d_ws, size_t ws_size,
                              hipStream_t stream)
{
    (void)in_sizes; (void)n_in; (void)out_size; (void)ws_size;

    const float* x  = (const float*)d_in[0];
    const float* Wq = (const float*)d_in[1];
    const float* Wk = (const float*)d_in[2];
    const float* Wv = (const float*)d_in[3];
    float* out = (float*)d_out;

    const int NB = 4, S = 2048, D = 1024;
    const long long SD  = (long long)S * D;     // 2,097,152
    const long long NSD = NB * SD;              // 8,388,608
    const long long SS  = (long long)S * S;     // 4,194,304

    // workspace (~150 MB): xb | Wt3 | QKVb | Vt | Sc
    ushort* xb   = (ushort*)d_ws;
    ushort* Wt3  = xb   + NSD;
    ushort* QKVb = Wt3  + 3 * (size_t)D * D;    // [8192][3072] bf16
    ushort* Vt   = QKVb + (size_t)NB * S * 3 * D;
    float*  Sc   = (float*)(Vt + NSD);          // NB*S*S fp32 (P overlays bf16)

    dim3 blk(256), blk5(512);

    // 1) conversions
    cvt_x<<<dim3((unsigned)(NSD / 4 / 256)), blk, 0, stream>>>(
        (const float4*)x, (ushort4*)xb, (int)(NSD / 4));
    cvt_wt<<<dim3(32, 32, 3), blk, 0, stream>>>(Wq, Wk, Wv, Wt3);

    // 2) merged QKV projection: [8192 x 3072 x 1024], 128x256 tiles
    dim3 gp(3 * D / 256, (unsigned)(NB * S / 128), 1);
    gemm_bf16<128, 256, 0, 1><<<gp, blk5, 0, stream>>>(
        xb, Wt3, nullptr, QKVb,
        3 * D, D, D, D, 0, 0, 0, 1.f);

    // 3) V -> Vt[b][d][s]
    transpose_v<<<dim3(D / 64, (unsigned)(NB * S / 64)), blk, 0, stream>>>(
        QKVb, Vt);

    // 4) scores = Q K^T / 32, 128x256 tiles, longest rows first
    dim3 gs(S / 256, S / 128, NB);
    gemm_bf16<128, 256, 1, 0><<<gs, blk5, 0, stream>>>(
        QKVb, QKVb + 1024, Sc, nullptr,
        S, D, 3 * D, 3 * D, (long long)S * 3 * D, (long long)S * 3 * D,
        SS, 0.03125f);

    // 5) softmax fp32 -> bf16 P in place
    softmax_bf16<<<dim3(S, NB), blk, 0, stream>>>(Sc);

    // 6) out = P V^T, 128x256 tiles, k-clipped, longest rows first
    dim3 gv(D / 256, S / 128, NB);
    gemm_bf16<128, 256, 2, 0><<<gv, blk5, 0, stream>>>(
        (const ushort*)Sc, Vt, out, nullptr,
        D, S, 2 * S, S, 2 * SS, SD, SD, 1.f);
}